// Round 13
// baseline (171.964 us; speedup 1.0000x reference)
//
#include <hip/hip_runtime.h>
#include <hip/hip_fp16.h>

#define N_NODES 50000
#define E_EDGES 800000
#define ETOT    (E_EDGES + N_NODES)   // edges + self loops = 850000
#define NF      128
#define HEADS   4
#define NC      32
#define LOG2E   1.44269504088896340736f
#define ASTRIDE 136                   // Abf row stride (ushort)
#define CAP     96                    // padded CSR row capacity (mean deg 17)

// radix CSR build
#define NBUCK   196                   // dst>>8 buckets
#define EPB     4096
#define NBLKA   ((ETOT + EPB - 1) / EPB)          // 208
#define PARTN   (NBUCK * NBLKA)                   // 40768
#define NTILES  ((PARTN + 255) / 256)             // 160
#define WCB     65                                // wconv blocks per layer

typedef __attribute__((ext_vector_type(8))) short short8v;
typedef __attribute__((ext_vector_type(4))) float f32x4;

__device__ inline ushort rne_bf16(float x) {
    uint u = __float_as_uint(x);
    return (ushort)((u + 0x7fff + ((u >> 16) & 1)) >> 16);
}
__device__ inline float h2f_lo(uint u) { return __half2float(__ushort_as_half((ushort)(u & 0xffffu))); }
__device__ inline float h2f_hi(uint u) { return __half2float(__ushort_as_half((ushort)(u >> 16))); }

// ---------------- wconv body: Wt[n][k] = bf16(W[k][n]) [144][144]; att folded rows ----------------
__device__ inline void wconv_body(int wb, int tid, const float* __restrict__ W,
                                  const float* __restrict__ att_src,
                                  const float* __restrict__ att_dst,
                                  ushort* __restrict__ Wt) {
    if (wb < 64) {
        int i = wb * 256 + tid;       // i = k*128 + n
        int k = i >> 7, n = i & 127;
        Wt[n * 144 + k] = rne_bf16(W[i]);
    } else {
        for (int j = tid; j < 1024; j += 256) {
            int k = j >> 3, o = j & 7;
            int h = o & 3;
            const float* av = (o < 4) ? att_src : att_dst;
            float s = 0.f;
            #pragma unroll
            for (int c = 0; c < 32; ++c) s += W[k * 128 + h * 32 + c] * av[h * 32 + c];
            Wt[(128 + o) * 144 + k] = rne_bf16(s * LOG2E);
        }
        for (int j = tid; j < 8 * 144; j += 256)
            Wt[(136 + (j / 144)) * 144 + (j % 144)] = 0;
    }
}

// ---------------- K1: hist(208) | wconv1(65) | wconv2(65); zeroes scan state ----------------
__global__ __launch_bounds__(256) void prep_kernel(const int* __restrict__ adj,
                                                   int* __restrict__ partials,
                                                   const float* __restrict__ W1,
                                                   const float* __restrict__ as1,
                                                   const float* __restrict__ ad1,
                                                   ushort* __restrict__ Wt1,
                                                   const float* __restrict__ W2,
                                                   const float* __restrict__ as2,
                                                   const float* __restrict__ ad2,
                                                   ushort* __restrict__ Wt2,
                                                   unsigned long long* __restrict__ tstate) {
    __shared__ int lc[NBUCK];
    int b = blockIdx.x, tid = threadIdx.x;
    if (b < NBLKA) {
        for (int i = tid; i < NBUCK; i += 256) lc[i] = 0;
        __syncthreads();
        int base = b * EPB;
        #pragma unroll
        for (int i = 0; i < EPB / 256; ++i) {
            int e = base + i * 256 + tid;
            if (e < ETOT) {
                int dst = (e < E_EDGES) ? adj[E_EDGES + e] : (e - E_EDGES);
                atomicAdd(&lc[dst >> 8], 1);
            }
        }
        __syncthreads();
        for (int i = tid; i < NBUCK; i += 256) partials[i * NBLKA + b] = lc[i];
    } else {
        if (b == NBLKA && tid < NTILES) tstate[tid] = 0ull;   // reset lookback state each call
        int wb = b - NBLKA;
        if (wb < WCB) wconv_body(wb, tid, W1, as1, ad1, Wt1);
        else          wconv_body(wb - WCB, tid, W2, as2, ad2, Wt2);
    }
}

// in-block inclusive scan over 256 threads
__device__ inline int block_incl_scan(int v, int* sh4) {
    int lane = threadIdx.x & 63, wid = threadIdx.x >> 6;
    int s = v;
    #pragma unroll
    for (int ofs = 1; ofs < 64; ofs <<= 1) {
        int t = __shfl_up(s, ofs);
        if (lane >= ofs) s += t;
    }
    if (lane == 63) sh4[wid] = s;
    __syncthreads();
    int add = 0;
    #pragma unroll
    for (int k = 0; k < 3; ++k) if (k < wid) add += sh4[k];
    return s + add;
}

// ---------------- K2: single-pass exclusive scan (decoupled lookback) ----------------
// tstate[tile] = (state<<32)|value; state 1=aggregate, 2=inclusive prefix. 160 blocks co-resident.
__global__ __launch_bounds__(256) void scan_lookback_kernel(const int* __restrict__ partials,
                                                            unsigned long long* __restrict__ tstate,
                                                            int* __restrict__ pscan) {
    __shared__ int sh4[4];
    __shared__ int btot_sh, prefix_sh;
    int tile = blockIdx.x, tid = threadIdx.x;
    int i = tile * 256 + tid;
    int v = (i < PARTN) ? partials[i] : 0;
    int s = block_incl_scan(v, sh4);
    if (tid == 255) btot_sh = s;
    __syncthreads();
    int btot = btot_sh;
    if (tid == 0) {
        if (tile == 0) {
            __hip_atomic_store(&tstate[0], (2ull << 32) | (unsigned)btot,
                               __ATOMIC_RELEASE, __HIP_MEMORY_SCOPE_AGENT);
            prefix_sh = 0;
        } else {
            __hip_atomic_store(&tstate[tile], (1ull << 32) | (unsigned)btot,
                               __ATOMIC_RELEASE, __HIP_MEMORY_SCOPE_AGENT);
            int pfx = 0;
            for (int p = tile - 1; p >= 0; --p) {
                unsigned long long st;
                do {
                    st = __hip_atomic_load(&tstate[p], __ATOMIC_ACQUIRE, __HIP_MEMORY_SCOPE_AGENT);
                } while ((st >> 32) == 0);
                pfx += (int)(st & 0xffffffffu);
                if ((st >> 32) == 2) break;
            }
            __hip_atomic_store(&tstate[tile], (2ull << 32) | (unsigned)(pfx + btot),
                               __ATOMIC_RELEASE, __HIP_MEMORY_SCOPE_AGENT);
            prefix_sh = pfx;
        }
    }
    __syncthreads();
    if (i < PARTN) pscan[i] = prefix_sh + s - v;   // exclusive
}

// ---------------- MFMA GEMM body: Hf = f16(X @ W); a_s/a_d from folded att cols ----------------
__device__ inline void gemm_body(ushort* __restrict__ Abf, int tid, int r0,
                                 const float* __restrict__ X, const ushort* __restrict__ Wt,
                                 ushort* __restrict__ Hf, float* __restrict__ a_s,
                                 float* __restrict__ a_d, int nrows) {
    {
        const float4* Xv = (const float4*)(X + (size_t)r0 * NF);
        int rleft = nrows - r0;
        #pragma unroll
        for (int p = 0; p < 8; ++p) {
            int i = p * 256 + tid;
            int row = i >> 5, c4 = i & 31;
            float4 v = (row < rleft) ? Xv[row * 32 + c4] : make_float4(0.f, 0.f, 0.f, 0.f);
            ushort4 hv;
            hv.x = rne_bf16(v.x); hv.y = rne_bf16(v.y);
            hv.z = rne_bf16(v.z); hv.w = rne_bf16(v.w);
            *(ushort4*)&Abf[row * ASTRIDE + c4 * 4] = hv;
        }
    }
    __syncthreads();

    int wv = tid >> 6;
    int l = tid & 63;
    int lr = l & 15;
    int lk = l >> 4;
    int rowb = wv * 16;

    short8v a[4];
    #pragma unroll
    for (int kc = 0; kc < 4; ++kc)
        a[kc] = *(const short8v*)&Abf[(rowb + lr) * ASTRIDE + kc * 32 + lk * 8];

    f32x4 acc[9];
    #pragma unroll
    for (int ct = 0; ct < 9; ++ct) acc[ct] = (f32x4){0.f, 0.f, 0.f, 0.f};

    #pragma unroll
    for (int ct = 0; ct < 9; ++ct) {
        #pragma unroll
        for (int kc = 0; kc < 4; ++kc) {
            short8v b = *(const short8v*)&Wt[(ct * 16 + lr) * 144 + kc * 32 + lk * 8];
            acc[ct] = __builtin_amdgcn_mfma_f32_16x16x32_bf16(a[kc], b, acc[ct], 0, 0, 0);
        }
    }

    int rbase = r0 + rowb + lk * 4;
    #pragma unroll
    for (int ct = 0; ct < 8; ++ct) {
        int col = ct * 16 + lr;
        #pragma unroll
        for (int ri = 0; ri < 4; ++ri) {
            int r = rbase + ri;
            if (r < nrows) Hf[(size_t)r * NF + col] = __half_as_ushort(__float2half(acc[ct][ri]));
        }
    }
    if (lr < 8) {
        #pragma unroll
        for (int ri = 0; ri < 4; ++ri) {
            int r = rbase + ri;
            if (r < nrows) {
                if (lr < 4) a_s[(size_t)r * 4 + lr] = acc[8][ri];
                else        a_d[(size_t)r * 4 + (lr - 4)] = acc[8][ri];
            }
        }
    }
}

// ---------------- K3: edge scatter(208) | gemm layer-1(782) ----------------
__global__ __launch_bounds__(256) void mid_kernel(const int* __restrict__ adj,
                                                  const int* __restrict__ pscan,
                                                  int2* __restrict__ ebuf,
                                                  const float* __restrict__ X,
                                                  const ushort* __restrict__ Wt,
                                                  ushort* __restrict__ Hf,
                                                  float* __restrict__ a_s,
                                                  float* __restrict__ a_d, int nrows) {
    __shared__ ushort Abf[64 * ASTRIDE];
    __shared__ int lc[NBUCK];
    int b = blockIdx.x, tid = threadIdx.x;
    if (b < NBLKA) {
        for (int i = tid; i < NBUCK; i += 256) lc[i] = 0;
        __syncthreads();
        int base = b * EPB;
        #pragma unroll
        for (int i = 0; i < EPB / 256; ++i) {
            int e = base + i * 256 + tid;
            if (e < ETOT) {
                int src, dst;
                if (e < E_EDGES) { src = adj[e]; dst = adj[E_EDGES + e]; }
                else             { src = dst = e - E_EDGES; }
                int bk = dst >> 8;
                int r = atomicAdd(&lc[bk], 1);
                ebuf[pscan[bk * NBLKA + b] + r] = make_int2(src, dst);
            }
        }
    } else {
        gemm_body(Abf, tid, (b - NBLKA) * 64, X, Wt, Hf, a_s, a_d, nrows);
    }
}

// ---------------- K6: standalone gemm (layer 2) ----------------
__global__ __launch_bounds__(256) void gemm_mfma_kernel(const float* __restrict__ X,
                                                        const ushort* __restrict__ Wt,
                                                        ushort* __restrict__ Hf,
                                                        float* __restrict__ a_s,
                                                        float* __restrict__ a_d, int nrows) {
    __shared__ ushort Abf[64 * ASTRIDE];
    gemm_body(Abf, threadIdx.x, blockIdx.x * 64, X, Wt, Hf, a_s, a_d, nrows);
}

// ---------------- K4: per-bucket dst ranks -> cnt + slots ----------------
__global__ __launch_bounds__(256) void pass_build_kernel(const int2* __restrict__ ebuf,
                                                         const int* __restrict__ pscan,
                                                         int* __restrict__ cnt,
                                                         int* __restrict__ slots) {
    __shared__ int lc[256];
    int tid = threadIdx.x;
    int b = blockIdx.x;
    lc[tid] = 0;
    __syncthreads();
    int base = pscan[b * NBLKA];
    int end  = (b == NBUCK - 1) ? ETOT : pscan[(b + 1) * NBLKA];
    for (int e = base + tid; e < end; e += 256) {
        int2 sd = ebuf[e];
        int d = sd.y & 255;
        int r = atomicAdd(&lc[d], 1);
        slots[(size_t)sd.y * CAP + r] = sd.x;
    }
    __syncthreads();
    int dst = b * 256 + tid;
    if (dst < N_NODES) cnt[dst] = lc[tid];
}

// ---------------- agg: per-node softmax + aggregation, quarter-per-edge, f16 H ----------------
__global__ __launch_bounds__(256) void agg_kernel(const ushort* __restrict__ Hf,
                                                  const float* __restrict__ a_s,
                                                  const float* __restrict__ a_d,
                                                  const int* __restrict__ cnt,
                                                  const int* __restrict__ slots,
                                                  const float* __restrict__ bias,
                                                  float* __restrict__ Out, int relu) {
    int lane = threadIdx.x & 63;
    int node = blockIdx.x * 4 + (threadIdx.x >> 6);
    if (node >= N_NODES) return;
    int q = lane >> 4;
    int t = lane & 15;
    int h = t >> 2;
    float adn = a_d[node * 4 + h];
    int deg = cnt[node];
    const int* row = slots + (size_t)node * CAP;
    const uint4* H4 = (const uint4*)Hf;
    float acc[8];
    #pragma unroll
    for (int k = 0; k < 8; ++k) acc[k] = 0.f;
    float denom = 0.f;

    for (int j = 0; j < deg; j += 16) {
        int sv[4]; float ev[4]; uint4 hv[4]; bool ok[4];
        #pragma unroll
        for (int u = 0; u < 4; ++u) {
            int idx = j + u * 4 + q;
            ok[u] = idx < deg;
            sv[u] = row[ok[u] ? idx : 0];
        }
        #pragma unroll
        for (int u = 0; u < 4; ++u) ev[u] = a_s[sv[u] * 4 + h];
        #pragma unroll
        for (int u = 0; u < 4; ++u) hv[u] = H4[(size_t)sv[u] * 16 + t];
        #pragma unroll
        for (int u = 0; u < 4; ++u) {
            float e = ev[u] + adn;
            e = (e > 0.f) ? e : 0.2f * e;          // leaky_relu (log2e scale commutes)
            float w = ok[u] ? exp2f(e) : 0.f;
            denom += w;
            acc[0] = fmaf(h2f_lo(hv[u].x), w, acc[0]);
            acc[1] = fmaf(h2f_hi(hv[u].x), w, acc[1]);
            acc[2] = fmaf(h2f_lo(hv[u].y), w, acc[2]);
            acc[3] = fmaf(h2f_hi(hv[u].y), w, acc[3]);
            acc[4] = fmaf(h2f_lo(hv[u].z), w, acc[4]);
            acc[5] = fmaf(h2f_hi(hv[u].z), w, acc[5]);
            acc[6] = fmaf(h2f_lo(hv[u].w), w, acc[6]);
            acc[7] = fmaf(h2f_hi(hv[u].w), w, acc[7]);
        }
    }
    #pragma unroll
    for (int ofs = 16; ofs < 64; ofs <<= 1) {
        denom += __shfl_xor(denom, ofs);
        #pragma unroll
        for (int k = 0; k < 8; ++k) acc[k] += __shfl_xor(acc[k], ofs);
    }
    if (q == 0) {
        float inv = 1.f / (denom + 1e-16f);
        float4 b0 = ((const float4*)bias)[t * 2];
        float4 b1 = ((const float4*)bias)[t * 2 + 1];
        float4 o0 = make_float4(acc[0] * inv + b0.x, acc[1] * inv + b0.y,
                                acc[2] * inv + b0.z, acc[3] * inv + b0.w);
        float4 o1 = make_float4(acc[4] * inv + b1.x, acc[5] * inv + b1.y,
                                acc[6] * inv + b1.z, acc[7] * inv + b1.w);
        if (relu) {
            o0.x = fmaxf(o0.x, 0.f); o0.y = fmaxf(o0.y, 0.f);
            o0.z = fmaxf(o0.z, 0.f); o0.w = fmaxf(o0.w, 0.f);
            o1.x = fmaxf(o1.x, 0.f); o1.y = fmaxf(o1.y, 0.f);
            o1.z = fmaxf(o1.z, 0.f); o1.w = fmaxf(o1.w, 0.f);
        }
        float4* orow = (float4*)(Out + (size_t)node * NF);
        orow[t * 2]     = o0;
        orow[t * 2 + 1] = o1;
    }
}

extern "C" void kernel_launch(void* const* d_in, const int* in_sizes, int n_in,
                              void* d_out, int out_size, void* d_ws, size_t ws_size,
                              hipStream_t stream) {
    const float* x        = (const float*)d_in[0];
    const int*   adj      = (const int*)  d_in[1];
    const float* W1       = (const float*)d_in[2];
    const float* att_src1 = (const float*)d_in[3];
    const float* att_dst1 = (const float*)d_in[4];
    const float* b1       = (const float*)d_in[5];
    const float* W2       = (const float*)d_in[6];
    const float* att_src2 = (const float*)d_in[7];
    const float* att_dst2 = (const float*)d_in[8];
    const float* b2       = (const float*)d_in[9];
    float* out = (float*)d_out;

    // workspace layout (8B-aligned chunks; parities verified)
    float* obuf = (float*)d_ws;                            // N*128 fp32
    float* a_s  = obuf + (size_t)N_NODES * NF;             // N*4
    float* a_d  = a_s + (size_t)N_NODES * HEADS;           // N*4
    ushort* Hf  = (ushort*)(a_d + (size_t)N_NODES * HEADS);// N*128 f16
    ushort* Wt1 = Hf + (size_t)N_NODES * NF;               // 144*144 bf16
    ushort* Wt2 = Wt1 + 144 * 144;                         // 144*144 bf16
    int* cnt      = (int*)(Wt2 + 144 * 144);               // N
    int* partials = cnt + N_NODES;                         // PARTN
    int* pscan    = partials + PARTN;                      // PARTN
    unsigned long long* tstate = (unsigned long long*)(pscan + PARTN);  // NTILES
    int2* ebuf  = (int2*)(tstate + NTILES);                // ETOT
    int* slots  = (int*)(ebuf + ETOT);                     // N*CAP

    // K1: bucket histogram | wconv W1 | wconv W2 (+ scan-state reset)
    prep_kernel<<<NBLKA + 2 * WCB, 256, 0, stream>>>(adj, partials,
                                                     W1, att_src1, att_dst1, Wt1,
                                                     W2, att_src2, att_dst2, Wt2, tstate);
    // K2: single-pass exclusive scan of partials
    scan_lookback_kernel<<<NTILES, 256, 0, stream>>>(partials, tstate, pscan);
    // K3: bucket-sort edges | gemm layer 1
    mid_kernel<<<NBLKA + (N_NODES + 63) / 64, 256, 0, stream>>>(adj, pscan, ebuf,
                                                                x, Wt1, Hf, a_s, a_d, N_NODES);
    // K4: per-dst ranks -> cnt + slots
    pass_build_kernel<<<NBUCK, 256, 0, stream>>>(ebuf, pscan, cnt, slots);
    // K5: agg layer 1
    agg_kernel<<<(N_NODES + 3) / 4, 256, 0, stream>>>(Hf, a_s, a_d, cnt, slots, b1, obuf, 1);
    // K6: gemm layer 2
    gemm_mfma_kernel<<<(N_NODES + 63) / 64, 256, 0, stream>>>(obuf, Wt2, Hf, a_s, a_d, N_NODES);
    // K7: agg layer 2
    agg_kernel<<<(N_NODES + 3) / 4, 256, 0, stream>>>(Hf, a_s, a_d, cnt, slots, b2, out, 0);
}

// Round 14
// 161.943 us; speedup vs baseline: 1.0619x; 1.0619x over previous
//
#include <hip/hip_runtime.h>
#include <hip/hip_fp16.h>

#define N_NODES 50000
#define E_EDGES 800000
#define ETOT    (E_EDGES + N_NODES)   // edges + self loops = 850000
#define NF      128
#define HEADS   4
#define NC      32
#define LOG2E   1.44269504088896340736f
#define ASTRIDE 136                   // Abf row stride (ushort)
#define CAP     96                    // padded CSR row capacity (mean deg 17; P(deg>=96)~1e-39)

// radix CSR build
#define NBUCK   196                   // dst>>8 buckets (49999>>8 = 195)
#define EPB     4096                  // edges per block in passes A/C
#define NBLKA   ((ETOT + EPB - 1) / EPB)          // 208
#define PARTN   (NBUCK * NBLKA)                   // 40768
#define NBLKS   ((PARTN + 255) / 256)             // 160

typedef __attribute__((ext_vector_type(8))) short short8v;
typedef __attribute__((ext_vector_type(4))) float f32x4;

__device__ inline ushort rne_bf16(float x) {
    uint u = __float_as_uint(x);
    return (ushort)((u + 0x7fff + ((u >> 16) & 1)) >> 16);
}
__device__ inline float h2f_lo(uint u) { return __half2float(__ushort_as_half((ushort)(u & 0xffffu))); }
__device__ inline float h2f_hi(uint u) { return __half2float(__ushort_as_half((ushort)(u >> 16))); }

// ---------------- radix CSR build (LDS atomics only) ----------------
__global__ __launch_bounds__(256) void pass_hist_kernel(const int* __restrict__ adj,
                                                        int* __restrict__ partials) {
    __shared__ int lc[NBUCK];
    int tid = threadIdx.x;
    for (int i = tid; i < NBUCK; i += 256) lc[i] = 0;
    __syncthreads();
    int base = blockIdx.x * EPB;
    #pragma unroll
    for (int i = 0; i < EPB / 256; ++i) {
        int e = base + i * 256 + tid;
        if (e < ETOT) {
            int dst = (e < E_EDGES) ? adj[E_EDGES + e] : (e - E_EDGES);
            atomicAdd(&lc[dst >> 8], 1);
        }
    }
    __syncthreads();
    for (int i = tid; i < NBUCK; i += 256) partials[i * NBLKA + blockIdx.x] = lc[i];
}

// in-block inclusive scan over 256 threads (wave shfl + LDS cross-wave)
__device__ inline int block_incl_scan(int v, int* sh4) {
    int lane = threadIdx.x & 63, wid = threadIdx.x >> 6;
    int s = v;
    #pragma unroll
    for (int ofs = 1; ofs < 64; ofs <<= 1) {
        int t = __shfl_up(s, ofs);
        if (lane >= ofs) s += t;
    }
    if (lane == 63) sh4[wid] = s;
    __syncthreads();
    int add = 0;
    #pragma unroll
    for (int k = 0; k < 3; ++k) if (k < wid) add += sh4[k];
    return s + add;
}

__global__ __launch_bounds__(256) void bsum2_kernel(const int* __restrict__ partials,
                                                    int* __restrict__ bsum) {
    __shared__ int sh4[4];
    int i = blockIdx.x * 256 + threadIdx.x;
    int v = (i < PARTN) ? partials[i] : 0;
    int s = block_incl_scan(v, sh4);
    if (threadIdx.x == 255) bsum[blockIdx.x] = s;
}

__global__ __launch_bounds__(256) void scan_bsums2_kernel(const int* __restrict__ bsum,
                                                          int* __restrict__ bofs) {
    __shared__ int sh4[4];
    int i = threadIdx.x;
    int v = (i < NBLKS) ? bsum[i] : 0;
    int s = block_incl_scan(v, sh4);
    if (i < NBLKS) bofs[i] = s - v;
}

__global__ __launch_bounds__(256) void scan_final2_kernel(const int* __restrict__ partials,
                                                          const int* __restrict__ bofs,
                                                          int* __restrict__ pscan) {
    __shared__ int sh4[4];
    int i = blockIdx.x * 256 + threadIdx.x;
    int v = (i < PARTN) ? partials[i] : 0;
    int s = block_incl_scan(v, sh4);
    if (i < PARTN) pscan[i] = bofs[blockIdx.x] + s - v;
}

// pass C: scatter edges into bucket-sorted ebuf via LDS ranks
__global__ __launch_bounds__(256) void pass_scatter_kernel(const int* __restrict__ adj,
                                                           const int* __restrict__ pscan,
                                                           int2* __restrict__ ebuf) {
    __shared__ int lc[NBUCK];
    int tid = threadIdx.x;
    for (int i = tid; i < NBUCK; i += 256) lc[i] = 0;
    __syncthreads();
    int base = blockIdx.x * EPB;
    #pragma unroll
    for (int i = 0; i < EPB / 256; ++i) {
        int e = base + i * 256 + tid;
        if (e < ETOT) {
            int src, dst;
            if (e < E_EDGES) { src = adj[e]; dst = adj[E_EDGES + e]; }
            else             { src = dst = e - E_EDGES; }
            int b = dst >> 8;
            int r = atomicAdd(&lc[b], 1);
            ebuf[pscan[b * NBLKA + blockIdx.x] + r] = make_int2(src, dst);
        }
    }
}

// pass D: one block per bucket -> per-dst ranks via 256 LDS counters; writes cnt + slots
__global__ __launch_bounds__(256) void pass_build_kernel(const int2* __restrict__ ebuf,
                                                         const int* __restrict__ pscan,
                                                         int* __restrict__ cnt,
                                                         int* __restrict__ slots) {
    __shared__ int lc[256];
    int tid = threadIdx.x;
    int b = blockIdx.x;
    lc[tid] = 0;
    __syncthreads();
    int base = pscan[b * NBLKA];
    int end  = (b == NBUCK - 1) ? ETOT : pscan[(b + 1) * NBLKA];
    for (int e = base + tid; e < end; e += 256) {
        int2 sd = ebuf[e];
        int d = sd.y & 255;
        int r = atomicAdd(&lc[d], 1);
        slots[(size_t)sd.y * CAP + r] = sd.x;
    }
    __syncthreads();
    int dst = b * 256 + tid;
    if (dst < N_NODES) cnt[dst] = lc[tid];
}

// ---------------- W convert: Wt[n][k] = bf16(W[k][n]), padded [144][144] ----------------
__global__ __launch_bounds__(256) void wconv_kernel(const float* __restrict__ W,
                                                    const float* __restrict__ att_src,
                                                    const float* __restrict__ att_dst,
                                                    ushort* __restrict__ Wt) {
    int b = blockIdx.x, tid = threadIdx.x;
    if (b < 64) {
        int i = b * 256 + tid;        // i = k*128 + n
        int k = i >> 7, n = i & 127;
        Wt[n * 144 + k] = rne_bf16(W[i]);
    } else {
        for (int j = tid; j < 1024; j += 256) {
            int k = j >> 3, o = j & 7;
            int h = o & 3;
            const float* av = (o < 4) ? att_src : att_dst;
            float s = 0.f;
            #pragma unroll
            for (int c = 0; c < 32; ++c) s += W[k * 128 + h * 32 + c] * av[h * 32 + c];
            Wt[(128 + o) * 144 + k] = rne_bf16(s * LOG2E);
        }
        for (int j = tid; j < 8 * 144; j += 256)
            Wt[(136 + (j / 144)) * 144 + (j % 144)] = 0;
    }
}

// ---------------- MFMA GEMM: Hf = f16(X @ W); a_s/a_d from folded att columns ----------------
__global__ __launch_bounds__(256) void gemm_mfma_kernel(const float* __restrict__ X,
                                                        const ushort* __restrict__ Wt,
                                                        ushort* __restrict__ Hf,
                                                        float* __restrict__ a_s,
                                                        float* __restrict__ a_d, int nrows) {
    __shared__ ushort Abf[64 * ASTRIDE];
    int tid = threadIdx.x;
    int r0 = blockIdx.x * 64;

    {
        const float4* Xv = (const float4*)(X + (size_t)r0 * NF);
        int rleft = nrows - r0;
        #pragma unroll
        for (int p = 0; p < 8; ++p) {
            int i = p * 256 + tid;
            int row = i >> 5, c4 = i & 31;
            float4 v = (row < rleft) ? Xv[row * 32 + c4] : make_float4(0.f, 0.f, 0.f, 0.f);
            ushort4 hv;
            hv.x = rne_bf16(v.x); hv.y = rne_bf16(v.y);
            hv.z = rne_bf16(v.z); hv.w = rne_bf16(v.w);
            *(ushort4*)&Abf[row * ASTRIDE + c4 * 4] = hv;
        }
    }
    __syncthreads();

    int wv = tid >> 6;
    int l = tid & 63;
    int lr = l & 15;
    int lk = l >> 4;
    int rowb = wv * 16;

    short8v a[4];
    #pragma unroll
    for (int kc = 0; kc < 4; ++kc)
        a[kc] = *(const short8v*)&Abf[(rowb + lr) * ASTRIDE + kc * 32 + lk * 8];

    f32x4 acc[9];
    #pragma unroll
    for (int ct = 0; ct < 9; ++ct) acc[ct] = (f32x4){0.f, 0.f, 0.f, 0.f};

    #pragma unroll
    for (int ct = 0; ct < 9; ++ct) {
        #pragma unroll
        for (int kc = 0; kc < 4; ++kc) {
            short8v b = *(const short8v*)&Wt[(ct * 16 + lr) * 144 + kc * 32 + lk * 8];
            acc[ct] = __builtin_amdgcn_mfma_f32_16x16x32_bf16(a[kc], b, acc[ct], 0, 0, 0);
        }
    }

    int rbase = r0 + rowb + lk * 4;
    #pragma unroll
    for (int ct = 0; ct < 8; ++ct) {
        int col = ct * 16 + lr;
        #pragma unroll
        for (int ri = 0; ri < 4; ++ri) {
            int r = rbase + ri;
            if (r < nrows) Hf[(size_t)r * NF + col] = __half_as_ushort(__float2half(acc[ct][ri]));
        }
    }
    if (lr < 8) {
        #pragma unroll
        for (int ri = 0; ri < 4; ++ri) {
            int r = rbase + ri;
            if (r < nrows) {
                if (lr < 4) a_s[(size_t)r * 4 + lr] = acc[8][ri];
                else        a_d[(size_t)r * 4 + (lr - 4)] = acc[8][ri];
            }
        }
    }
}

// ---------------- per-node softmax + aggregation, quarter-per-edge, f16 H ----------------
__global__ __launch_bounds__(256) void agg_kernel(const ushort* __restrict__ Hf,
                                                  const float* __restrict__ a_s,
                                                  const float* __restrict__ a_d,
                                                  const int* __restrict__ cnt,
                                                  const int* __restrict__ slots,
                                                  const float* __restrict__ bias,
                                                  float* __restrict__ Out, int relu) {
    int lane = threadIdx.x & 63;
    int node = blockIdx.x * 4 + (threadIdx.x >> 6);
    if (node >= N_NODES) return;
    int q = lane >> 4;
    int t = lane & 15;
    int h = t >> 2;
    float adn = a_d[node * 4 + h];
    int deg = cnt[node];
    const int* row = slots + (size_t)node * CAP;
    const uint4* H4 = (const uint4*)Hf;
    float acc[8];
    #pragma unroll
    for (int k = 0; k < 8; ++k) acc[k] = 0.f;
    float denom = 0.f;

    for (int j = 0; j < deg; j += 16) {
        int sv[4]; float ev[4]; uint4 hv[4]; bool ok[4];
        #pragma unroll
        for (int u = 0; u < 4; ++u) {
            int idx = j + u * 4 + q;
            ok[u] = idx < deg;
            sv[u] = row[ok[u] ? idx : 0];
        }
        #pragma unroll
        for (int u = 0; u < 4; ++u) ev[u] = a_s[sv[u] * 4 + h];
        #pragma unroll
        for (int u = 0; u < 4; ++u) hv[u] = H4[(size_t)sv[u] * 16 + t];
        #pragma unroll
        for (int u = 0; u < 4; ++u) {
            float e = ev[u] + adn;
            e = (e > 0.f) ? e : 0.2f * e;          // leaky_relu (log2e scale commutes)
            float w = ok[u] ? exp2f(e) : 0.f;      // |e| small; no max-subtraction needed
            denom += w;
            acc[0] = fmaf(h2f_lo(hv[u].x), w, acc[0]);
            acc[1] = fmaf(h2f_hi(hv[u].x), w, acc[1]);
            acc[2] = fmaf(h2f_lo(hv[u].y), w, acc[2]);
            acc[3] = fmaf(h2f_hi(hv[u].y), w, acc[3]);
            acc[4] = fmaf(h2f_lo(hv[u].z), w, acc[4]);
            acc[5] = fmaf(h2f_hi(hv[u].z), w, acc[5]);
            acc[6] = fmaf(h2f_lo(hv[u].w), w, acc[6]);
            acc[7] = fmaf(h2f_hi(hv[u].w), w, acc[7]);
        }
    }
    #pragma unroll
    for (int ofs = 16; ofs < 64; ofs <<= 1) {
        denom += __shfl_xor(denom, ofs);
        #pragma unroll
        for (int k = 0; k < 8; ++k) acc[k] += __shfl_xor(acc[k], ofs);
    }
    if (q == 0) {
        float inv = 1.f / (denom + 1e-16f);
        float4 b0 = ((const float4*)bias)[t * 2];
        float4 b1 = ((const float4*)bias)[t * 2 + 1];
        float4 o0 = make_float4(acc[0] * inv + b0.x, acc[1] * inv + b0.y,
                                acc[2] * inv + b0.z, acc[3] * inv + b0.w);
        float4 o1 = make_float4(acc[4] * inv + b1.x, acc[5] * inv + b1.y,
                                acc[6] * inv + b1.z, acc[7] * inv + b1.w);
        if (relu) {
            o0.x = fmaxf(o0.x, 0.f); o0.y = fmaxf(o0.y, 0.f);
            o0.z = fmaxf(o0.z, 0.f); o0.w = fmaxf(o0.w, 0.f);
            o1.x = fmaxf(o1.x, 0.f); o1.y = fmaxf(o1.y, 0.f);
            o1.z = fmaxf(o1.z, 0.f); o1.w = fmaxf(o1.w, 0.f);
        }
        float4* orow = (float4*)(Out + (size_t)node * NF);
        orow[t * 2]     = o0;
        orow[t * 2 + 1] = o1;
    }
}

extern "C" void kernel_launch(void* const* d_in, const int* in_sizes, int n_in,
                              void* d_out, int out_size, void* d_ws, size_t ws_size,
                              hipStream_t stream) {
    const float* x        = (const float*)d_in[0];
    const int*   adj      = (const int*)  d_in[1];
    const float* W1       = (const float*)d_in[2];
    const float* att_src1 = (const float*)d_in[3];
    const float* att_dst1 = (const float*)d_in[4];
    const float* b1       = (const float*)d_in[5];
    const float* W2       = (const float*)d_in[6];
    const float* att_src2 = (const float*)d_in[7];
    const float* att_dst2 = (const float*)d_in[8];
    const float* b2       = (const float*)d_in[9];
    float* out = (float*)d_out;

    // workspace layout
    float* obuf = (float*)d_ws;                            // N*128 fp32
    float* a_s  = obuf + (size_t)N_NODES * NF;             // N*4
    float* a_d  = a_s + (size_t)N_NODES * HEADS;           // N*4
    ushort* Hf  = (ushort*)(a_d + (size_t)N_NODES * HEADS);// N*128 f16
    ushort* Wt  = Hf + (size_t)N_NODES * NF;               // 144*144 bf16
    int* cnt     = (int*)(Wt + 144 * 144);                 // N
    int* slots   = cnt + N_NODES;                          // N*CAP
    int* partials= slots + (size_t)N_NODES * CAP;          // PARTN
    int* pscan   = partials + PARTN;                       // PARTN
    int* bsum    = pscan + PARTN;                          // NBLKS
    int* bofs    = bsum + NBLKS;                           // NBLKS
    int2* ebuf   = (int2*)(bofs + NBLKS + 2);              // ETOT (8B aligned)

    // ---- CSR build: radix-bucketed, LDS atomics only ----
    pass_hist_kernel<<<NBLKA, 256, 0, stream>>>(adj, partials);
    bsum2_kernel<<<NBLKS, 256, 0, stream>>>(partials, bsum);
    scan_bsums2_kernel<<<1, 256, 0, stream>>>(bsum, bofs);
    scan_final2_kernel<<<NBLKS, 256, 0, stream>>>(partials, bofs, pscan);
    pass_scatter_kernel<<<NBLKA, 256, 0, stream>>>(adj, pscan, ebuf);
    pass_build_kernel<<<NBUCK, 256, 0, stream>>>(ebuf, pscan, cnt, slots);

    // ---- layer 1 ----
    wconv_kernel<<<65, 256, 0, stream>>>(W1, att_src1, att_dst1, Wt);
    gemm_mfma_kernel<<<(N_NODES + 63) / 64, 256, 0, stream>>>(x, Wt, Hf, a_s, a_d, N_NODES);
    agg_kernel<<<(N_NODES + 3) / 4, 256, 0, stream>>>(Hf, a_s, a_d, cnt, slots, b1, obuf, 1);

    // ---- layer 2 ----
    wconv_kernel<<<65, 256, 0, stream>>>(W2, att_src2, att_dst2, Wt);
    gemm_mfma_kernel<<<(N_NODES + 63) / 64, 256, 0, stream>>>(obuf, Wt, Hf, a_s, a_d, N_NODES);
    agg_kernel<<<(N_NODES + 3) / 4, 256, 0, stream>>>(Hf, a_s, a_d, cnt, slots, b2, out, 0);
}

// Round 15
// 149.654 us; speedup vs baseline: 1.1491x; 1.0821x over previous
//
#include <hip/hip_runtime.h>
#include <hip/hip_fp16.h>

#define N_NODES 50000
#define E_EDGES 800000
#define ETOT    (E_EDGES + N_NODES)   // edges + self loops = 850000
#define NF      128
#define HEADS   4
#define NC      32
#define LOG2E   1.44269504088896340736f
#define ASTRIDE 136                   // Abf row stride (ushort)
#define CAP     96                    // padded CSR row capacity (mean deg 17; P(deg>=96)~1e-39)

// radix CSR build
#define NBUCK   196                   // dst>>8 buckets (49999>>8 = 195)
#define EPB     4096                  // edges per block in passes A/C
#define NBLKA   ((ETOT + EPB - 1) / EPB)          // 208
#define PARTN   (NBUCK * NBLKA)                   // 40768
#define NBLKS   ((PARTN + 255) / 256)             // 160
#define WCB     65                                // wconv blocks per layer

typedef __attribute__((ext_vector_type(8))) short short8v;
typedef __attribute__((ext_vector_type(4))) float f32x4;

__device__ inline ushort rne_bf16(float x) {
    uint u = __float_as_uint(x);
    return (ushort)((u + 0x7fff + ((u >> 16) & 1)) >> 16);
}
__device__ inline float h2f_lo(uint u) { return __half2float(__ushort_as_half((ushort)(u & 0xffffu))); }
__device__ inline float h2f_hi(uint u) { return __half2float(__ushort_as_half((ushort)(u >> 16))); }

// ---------------- wconv body: Wt[n][k] = bf16(W[k][n]) [144][144]; att folded rows ----------------
__device__ inline void wconv_body(int wb, int tid, const float* __restrict__ W,
                                  const float* __restrict__ att_src,
                                  const float* __restrict__ att_dst,
                                  ushort* __restrict__ Wt) {
    if (wb < 64) {
        int i = wb * 256 + tid;       // i = k*128 + n
        int k = i >> 7, n = i & 127;
        Wt[n * 144 + k] = rne_bf16(W[i]);
    } else {
        for (int j = tid; j < 1024; j += 256) {
            int k = j >> 3, o = j & 7;
            int h = o & 3;
            const float* av = (o < 4) ? att_src : att_dst;
            float s = 0.f;
            #pragma unroll
            for (int c = 0; c < 32; ++c) s += W[k * 128 + h * 32 + c] * av[h * 32 + c];
            Wt[(128 + o) * 144 + k] = rne_bf16(s * LOG2E);
        }
        for (int j = tid; j < 8 * 144; j += 256)
            Wt[(136 + (j / 144)) * 144 + (j % 144)] = 0;
    }
}

// ---------------- K1: bucket hist(208) | wconv1(65) | wconv2(65) ----------------
__global__ __launch_bounds__(256) void prep_kernel(const int* __restrict__ adj,
                                                   int* __restrict__ partials,
                                                   const float* __restrict__ W1,
                                                   const float* __restrict__ as1,
                                                   const float* __restrict__ ad1,
                                                   ushort* __restrict__ Wt1,
                                                   const float* __restrict__ W2,
                                                   const float* __restrict__ as2,
                                                   const float* __restrict__ ad2,
                                                   ushort* __restrict__ Wt2) {
    __shared__ int lc[NBUCK];
    int b = blockIdx.x, tid = threadIdx.x;
    if (b < NBLKA) {
        for (int i = tid; i < NBUCK; i += 256) lc[i] = 0;
        __syncthreads();
        int base = b * EPB;
        #pragma unroll
        for (int i = 0; i < EPB / 256; ++i) {
            int e = base + i * 256 + tid;
            if (e < ETOT) {
                int dst = (e < E_EDGES) ? adj[E_EDGES + e] : (e - E_EDGES);
                atomicAdd(&lc[dst >> 8], 1);
            }
        }
        __syncthreads();
        for (int i = tid; i < NBUCK; i += 256) partials[i * NBLKA + b] = lc[i];
    } else {
        int wb = b - NBLKA;
        if (wb < WCB) wconv_body(wb, tid, W1, as1, ad1, Wt1);
        else          wconv_body(wb - WCB, tid, W2, as2, ad2, Wt2);
    }
}

// in-block inclusive scan over 256 threads (wave shfl + LDS cross-wave)
__device__ inline int block_incl_scan(int v, int* sh4) {
    int lane = threadIdx.x & 63, wid = threadIdx.x >> 6;
    int s = v;
    #pragma unroll
    for (int ofs = 1; ofs < 64; ofs <<= 1) {
        int t = __shfl_up(s, ofs);
        if (lane >= ofs) s += t;
    }
    if (lane == 63) sh4[wid] = s;
    __syncthreads();
    int add = 0;
    #pragma unroll
    for (int k = 0; k < 3; ++k) if (k < wid) add += sh4[k];
    return s + add;
}

__global__ __launch_bounds__(256) void bsum2_kernel(const int* __restrict__ partials,
                                                    int* __restrict__ bsum) {
    __shared__ int sh4[4];
    int i = blockIdx.x * 256 + threadIdx.x;
    int v = (i < PARTN) ? partials[i] : 0;
    int s = block_incl_scan(v, sh4);
    if (threadIdx.x == 255) bsum[blockIdx.x] = s;
}

__global__ __launch_bounds__(256) void scan_bsums2_kernel(const int* __restrict__ bsum,
                                                          int* __restrict__ bofs) {
    __shared__ int sh4[4];
    int i = threadIdx.x;
    int v = (i < NBLKS) ? bsum[i] : 0;
    int s = block_incl_scan(v, sh4);
    if (i < NBLKS) bofs[i] = s - v;
}

__global__ __launch_bounds__(256) void scan_final2_kernel(const int* __restrict__ partials,
                                                          const int* __restrict__ bofs,
                                                          int* __restrict__ pscan) {
    __shared__ int sh4[4];
    int i = blockIdx.x * 256 + threadIdx.x;
    int v = (i < PARTN) ? partials[i] : 0;
    int s = block_incl_scan(v, sh4);
    if (i < PARTN) pscan[i] = bofs[blockIdx.x] + s - v;
}

// pass C: scatter edges into bucket-sorted ebuf via LDS ranks
__global__ __launch_bounds__(256) void pass_scatter_kernel(const int* __restrict__ adj,
                                                           const int* __restrict__ pscan,
                                                           int2* __restrict__ ebuf) {
    __shared__ int lc[NBUCK];
    int tid = threadIdx.x;
    for (int i = tid; i < NBUCK; i += 256) lc[i] = 0;
    __syncthreads();
    int base = blockIdx.x * EPB;
    #pragma unroll
    for (int i = 0; i < EPB / 256; ++i) {
        int e = base + i * 256 + tid;
        if (e < ETOT) {
            int src, dst;
            if (e < E_EDGES) { src = adj[e]; dst = adj[E_EDGES + e]; }
            else             { src = dst = e - E_EDGES; }
            int b = dst >> 8;
            int r = atomicAdd(&lc[b], 1);
            ebuf[pscan[b * NBLKA + blockIdx.x] + r] = make_int2(src, dst);
        }
    }
}

// pass D: one block per bucket -> per-dst ranks via 256 LDS counters; writes cnt + slots
__global__ __launch_bounds__(256) void pass_build_kernel(const int2* __restrict__ ebuf,
                                                         const int* __restrict__ pscan,
                                                         int* __restrict__ cnt,
                                                         int* __restrict__ slots) {
    __shared__ int lc[256];
    int tid = threadIdx.x;
    int b = blockIdx.x;
    lc[tid] = 0;
    __syncthreads();
    int base = pscan[b * NBLKA];
    int end  = (b == NBUCK - 1) ? ETOT : pscan[(b + 1) * NBLKA];
    for (int e = base + tid; e < end; e += 256) {
        int2 sd = ebuf[e];
        int d = sd.y & 255;
        int r = atomicAdd(&lc[d], 1);
        slots[(size_t)sd.y * CAP + r] = sd.x;
    }
    __syncthreads();
    int dst = b * 256 + tid;
    if (dst < N_NODES) cnt[dst] = lc[tid];
}

// ---------------- MFMA GEMM: Hf = f16(X @ W); a_s/a_d from folded att columns ----------------
__global__ __launch_bounds__(256) void gemm_mfma_kernel(const float* __restrict__ X,
                                                        const ushort* __restrict__ Wt,
                                                        ushort* __restrict__ Hf,
                                                        float* __restrict__ a_s,
                                                        float* __restrict__ a_d, int nrows) {
    __shared__ ushort Abf[64 * ASTRIDE];
    int tid = threadIdx.x;
    int r0 = blockIdx.x * 64;

    {
        const float4* Xv = (const float4*)(X + (size_t)r0 * NF);
        int rleft = nrows - r0;
        #pragma unroll
        for (int p = 0; p < 8; ++p) {
            int i = p * 256 + tid;
            int row = i >> 5, c4 = i & 31;
            float4 v = (row < rleft) ? Xv[row * 32 + c4] : make_float4(0.f, 0.f, 0.f, 0.f);
            ushort4 hv;
            hv.x = rne_bf16(v.x); hv.y = rne_bf16(v.y);
            hv.z = rne_bf16(v.z); hv.w = rne_bf16(v.w);
            *(ushort4*)&Abf[row * ASTRIDE + c4 * 4] = hv;
        }
    }
    __syncthreads();

    int wv = tid >> 6;
    int l = tid & 63;
    int lr = l & 15;
    int lk = l >> 4;
    int rowb = wv * 16;

    short8v a[4];
    #pragma unroll
    for (int kc = 0; kc < 4; ++kc)
        a[kc] = *(const short8v*)&Abf[(rowb + lr) * ASTRIDE + kc * 32 + lk * 8];

    f32x4 acc[9];
    #pragma unroll
    for (int ct = 0; ct < 9; ++ct) acc[ct] = (f32x4){0.f, 0.f, 0.f, 0.f};

    #pragma unroll
    for (int ct = 0; ct < 9; ++ct) {
        #pragma unroll
        for (int kc = 0; kc < 4; ++kc) {
            short8v b = *(const short8v*)&Wt[(ct * 16 + lr) * 144 + kc * 32 + lk * 8];
            acc[ct] = __builtin_amdgcn_mfma_f32_16x16x32_bf16(a[kc], b, acc[ct], 0, 0, 0);
        }
    }

    int rbase = r0 + rowb + lk * 4;
    #pragma unroll
    for (int ct = 0; ct < 8; ++ct) {
        int col = ct * 16 + lr;
        #pragma unroll
        for (int ri = 0; ri < 4; ++ri) {
            int r = rbase + ri;
            if (r < nrows) Hf[(size_t)r * NF + col] = __half_as_ushort(__float2half(acc[ct][ri]));
        }
    }
    if (lr < 8) {
        #pragma unroll
        for (int ri = 0; ri < 4; ++ri) {
            int r = rbase + ri;
            if (r < nrows) {
                if (lr < 4) a_s[(size_t)r * 4 + lr] = acc[8][ri];
                else        a_d[(size_t)r * 4 + (lr - 4)] = acc[8][ri];
            }
        }
    }
}

// ---------------- per-node softmax + aggregation, quarter-per-edge, granule 8 ----------------
__global__ __launch_bounds__(256) void agg_kernel(const ushort* __restrict__ Hf,
                                                  const float* __restrict__ a_s,
                                                  const float* __restrict__ a_d,
                                                  const int* __restrict__ cnt,
                                                  const int* __restrict__ slots,
                                                  const float* __restrict__ bias,
                                                  float* __restrict__ Out, int relu) {
    int lane = threadIdx.x & 63;
    int node = blockIdx.x * 4 + (threadIdx.x >> 6);
    if (node >= N_NODES) return;
    int q = lane >> 4;
    int t = lane & 15;
    int h = t >> 2;
    float adn = a_d[node * 4 + h];
    int deg = cnt[node];
    const int* row = slots + (size_t)node * CAP;
    const uint4* H4 = (const uint4*)Hf;
    float acc[8];
    #pragma unroll
    for (int k = 0; k < 8; ++k) acc[k] = 0.f;
    float denom = 0.f;

    // granule 8: quarter q handles edges j+q and j+4+q (less padding waste at deg~17
    // than granule 16, still 8 gathers in flight per wave-step)
    for (int j = 0; j < deg; j += 8) {
        int sv[2]; float ev[2]; uint4 hv[2]; bool ok[2];
        #pragma unroll
        for (int u = 0; u < 2; ++u) {
            int idx = j + u * 4 + q;
            ok[u] = idx < deg;
            sv[u] = row[ok[u] ? idx : 0];
        }
        #pragma unroll
        for (int u = 0; u < 2; ++u) ev[u] = a_s[sv[u] * 4 + h];
        #pragma unroll
        for (int u = 0; u < 2; ++u) hv[u] = H4[(size_t)sv[u] * 16 + t];
        #pragma unroll
        for (int u = 0; u < 2; ++u) {
            float e = ev[u] + adn;
            e = (e > 0.f) ? e : 0.2f * e;          // leaky_relu (log2e scale commutes)
            float w = ok[u] ? exp2f(e) : 0.f;      // |e| small; no max-subtraction needed
            denom += w;
            acc[0] = fmaf(h2f_lo(hv[u].x), w, acc[0]);
            acc[1] = fmaf(h2f_hi(hv[u].x), w, acc[1]);
            acc[2] = fmaf(h2f_lo(hv[u].y), w, acc[2]);
            acc[3] = fmaf(h2f_hi(hv[u].y), w, acc[3]);
            acc[4] = fmaf(h2f_lo(hv[u].z), w, acc[4]);
            acc[5] = fmaf(h2f_hi(hv[u].z), w, acc[5]);
            acc[6] = fmaf(h2f_lo(hv[u].w), w, acc[6]);
            acc[7] = fmaf(h2f_hi(hv[u].w), w, acc[7]);
        }
    }
    #pragma unroll
    for (int ofs = 16; ofs < 64; ofs <<= 1) {
        denom += __shfl_xor(denom, ofs);
        #pragma unroll
        for (int k = 0; k < 8; ++k) acc[k] += __shfl_xor(acc[k], ofs);
    }
    if (q == 0) {
        float inv = 1.f / (denom + 1e-16f);
        float4 b0 = ((const float4*)bias)[t * 2];
        float4 b1 = ((const float4*)bias)[t * 2 + 1];
        float4 o0 = make_float4(acc[0] * inv + b0.x, acc[1] * inv + b0.y,
                                acc[2] * inv + b0.z, acc[3] * inv + b0.w);
        float4 o1 = make_float4(acc[4] * inv + b1.x, acc[5] * inv + b1.y,
                                acc[6] * inv + b1.z, acc[7] * inv + b1.w);
        if (relu) {
            o0.x = fmaxf(o0.x, 0.f); o0.y = fmaxf(o0.y, 0.f);
            o0.z = fmaxf(o0.z, 0.f); o0.w = fmaxf(o0.w, 0.f);
            o1.x = fmaxf(o1.x, 0.f); o1.y = fmaxf(o1.y, 0.f);
            o1.z = fmaxf(o1.z, 0.f); o1.w = fmaxf(o1.w, 0.f);
        }
        float4* orow = (float4*)(Out + (size_t)node * NF);
        orow[t * 2]     = o0;
        orow[t * 2 + 1] = o1;
    }
}

extern "C" void kernel_launch(void* const* d_in, const int* in_sizes, int n_in,
                              void* d_out, int out_size, void* d_ws, size_t ws_size,
                              hipStream_t stream) {
    const float* x        = (const float*)d_in[0];
    const int*   adj      = (const int*)  d_in[1];
    const float* W1       = (const float*)d_in[2];
    const float* att_src1 = (const float*)d_in[3];
    const float* att_dst1 = (const float*)d_in[4];
    const float* b1       = (const float*)d_in[5];
    const float* W2       = (const float*)d_in[6];
    const float* att_src2 = (const float*)d_in[7];
    const float* att_dst2 = (const float*)d_in[8];
    const float* b2       = (const float*)d_in[9];
    float* out = (float*)d_out;

    // workspace layout
    float* obuf = (float*)d_ws;                            // N*128 fp32
    float* a_s  = obuf + (size_t)N_NODES * NF;             // N*4
    float* a_d  = a_s + (size_t)N_NODES * HEADS;           // N*4
    ushort* Hf  = (ushort*)(a_d + (size_t)N_NODES * HEADS);// N*128 f16
    ushort* Wt1 = Hf + (size_t)N_NODES * NF;               // 144*144 bf16
    ushort* Wt2 = Wt1 + 144 * 144;                         // 144*144 bf16
    int* cnt     = (int*)(Wt2 + 144 * 144);                // N
    int* slots   = cnt + N_NODES;                          // N*CAP
    int* partials= slots + (size_t)N_NODES * CAP;          // PARTN
    int* pscan   = partials + PARTN;                       // PARTN
    int* bsum    = pscan + PARTN;                          // NBLKS
    int* bofs    = bsum + NBLKS;                           // NBLKS
    int2* ebuf   = (int2*)(bofs + NBLKS + 2);              // ETOT (8B aligned)

    // K1: bucket histogram | wconv W1 | wconv W2
    prep_kernel<<<NBLKA + 2 * WCB, 256, 0, stream>>>(adj, partials,
                                                     W1, att_src1, att_dst1, Wt1,
                                                     W2, att_src2, att_dst2, Wt2);
    // 3-phase scan of partials
    bsum2_kernel<<<NBLKS, 256, 0, stream>>>(partials, bsum);
    scan_bsums2_kernel<<<1, 256, 0, stream>>>(bsum, bofs);
    scan_final2_kernel<<<NBLKS, 256, 0, stream>>>(partials, bofs, pscan);
    // bucket-sort edges, then per-dst ranks -> cnt + slots
    pass_scatter_kernel<<<NBLKA, 256, 0, stream>>>(adj, pscan, ebuf);
    pass_build_kernel<<<NBUCK, 256, 0, stream>>>(ebuf, pscan, cnt, slots);

    // ---- layer 1 ----
    gemm_mfma_kernel<<<(N_NODES + 63) / 64, 256, 0, stream>>>(x, Wt1, Hf, a_s, a_d, N_NODES);
    agg_kernel<<<(N_NODES + 3) / 4, 256, 0, stream>>>(Hf, a_s, a_d, cnt, slots, b1, obuf, 1);

    // ---- layer 2 ----
    gemm_mfma_kernel<<<(N_NODES + 63) / 64, 256, 0, stream>>>(obuf, Wt2, Hf, a_s, a_d, N_NODES);
    agg_kernel<<<(N_NODES + 3) / 4, 256, 0, stream>>>(Hf, a_s, a_d, cnt, slots, b2, out, 0);
}